// Round 2
// baseline (63.507 us; speedup 1.0000x reference)
//
#include <hip/hip_runtime.h>
#include <stdint.h>

#define B_DIM 2048
#define K_DIM 2048
#define N_PACK 4096

typedef int v4i __attribute__((ext_vector_type(4)));

__device__ __forceinline__ float fqf(float x) {
    float q = rintf(x * 32.0f);
    q = fminf(fmaxf(q, -128.0f), 127.0f);
    return q * 0.03125f;
}
__device__ __forceinline__ int q8i(float x) {
    float q = rintf(x * 32.0f);
    q = fminf(fmaxf(q, -128.0f), 127.0f);
    return (int)q;
}
__device__ __forceinline__ float fsigm(float x) {
    return __fdividef(1.0f, 1.0f + __expf(-x));
}
__device__ __forceinline__ float ftanh(float x) {
    return __fdividef(2.0f, 1.0f + __expf(-2.0f * x)) - 1.0f;
}

// Quantize + pack everything. R10 change: W is packed into MFMA-FRAGMENT order
// so the GEMM loads B straight from global (bypassing LDS -> kills the LDS
// throughput bound measured in R8/R9).
//
// B2 layout: for col-group c0 (16 packed cols), 64B-k-chunk c (0..31):
//   byte addr = c0*32768 + c*1024 + l*16  holds  B[c0*16 + (l&15)][c*64 + (l>>4)*16 .. +16]
// which is EXACTLY the verified 16x16x64 i8 B-fragment byte map -> a wave's
// b-frag load is one fully-coalesced global_load_dwordx4 at base + l*16.
//
//  blocks [0, 2048)        : Xh rows  -> Xhq[m][k] int8 (unchanged)
//  blocks [2048, 2304)     : W groups -> B2 fragment-packed (16 rows/block via LDS transpose)
//  block  2304             : bias     -> bqp[j*4 + gate]
__global__ __launch_bounds__(256) void quant_pack(
    const float* __restrict__ X, const float* __restrict__ hI,
    const float* __restrict__ W, const float* __restrict__ bias,
    int8_t* __restrict__ Xhq, int8_t* __restrict__ Wq2, float* __restrict__ bqp)
{
    __shared__ __align__(16) char lds[16 * 2064];   // 16 rows x 2048B (+16B pad vs bank conflicts)
    const int bid = blockIdx.x;
    const int t = threadIdx.x;
    if (bid < B_DIM) {
        const int m = bid;
        const int k0 = t * 8;
        const float* src = (k0 < 1024) ? (X + (size_t)m * 1024 + k0)
                                       : (hI + (size_t)m * 1024 + (k0 - 1024));
        float4 v0 = *(const float4*)src;
        float4 v1 = *(const float4*)(src + 4);
        union { int8_t c[8]; int64_t ll; } u;
        u.c[0] = (int8_t)q8i(v0.x); u.c[1] = (int8_t)q8i(v0.y);
        u.c[2] = (int8_t)q8i(v0.z); u.c[3] = (int8_t)q8i(v0.w);
        u.c[4] = (int8_t)q8i(v1.x); u.c[5] = (int8_t)q8i(v1.y);
        u.c[6] = (int8_t)q8i(v1.z); u.c[7] = (int8_t)q8i(v1.w);
        *(int64_t*)(Xhq + (size_t)m * K_DIM + k0) = u.ll;
    } else if (bid < B_DIM + 256) {
        const int c0 = bid - B_DIM;                 // col-group: packed cols [c0*16, c0*16+16)
        // phase 1: quantize 16 source rows into LDS (reads fully coalesced).
        // packed p = c0*16 + pi -> gate = pi&3, j = c0*4 + (pi>>2), src row = gate*1024 + j
        for (int pi = 0; pi < 16; ++pi) {
            const int r = (pi & 3) * 1024 + c0 * 4 + (pi >> 2);
            const float* src = W + (size_t)r * K_DIM + t * 8;
            float4 v0 = *(const float4*)src;
            float4 v1 = *(const float4*)(src + 4);
            union { int8_t c[8]; int64_t ll; } u;
            u.c[0] = (int8_t)q8i(v0.x); u.c[1] = (int8_t)q8i(v0.y);
            u.c[2] = (int8_t)q8i(v0.z); u.c[3] = (int8_t)q8i(v0.w);
            u.c[4] = (int8_t)q8i(v1.x); u.c[5] = (int8_t)q8i(v1.y);
            u.c[6] = (int8_t)q8i(v1.z); u.c[7] = (int8_t)q8i(v1.w);
            *(int64_t*)(lds + pi * 2064 + t * 8) = u.ll;
        }
        __syncthreads();
        // phase 2: emit 32 chunks of 1KB, fragment-ordered, writes coalesced.
        const int w = t >> 6, l = t & 63;
        #pragma unroll
        for (int rd = 0; rd < 8; ++rd) {
            const int c = rd * 4 + w;               // 64B-k-chunk id, 0..31
            v4i val = *(const v4i*)(lds + (l & 15) * 2064 + c * 64 + (l >> 4) * 16);
            *(v4i*)(Wq2 + ((size_t)c0 << 15) + c * 1024 + l * 16) = val;
        }
    } else {
        for (int idx = t; idx < N_PACK; idx += 256) {
            const int gate = idx >> 10, j = idx & 1023;
            bqp[(j << 2) | gate] = fqf(bias[idx]);
        }
    }
}

// GEMM C[2048][4096p] = Xhq @ Wq^T (int8 -> i32, exact), fused LSTM epilogue.
// R10: B bypasses LDS (fragment-packed global loads). A through LDS dbuf.
//   BM=128, BN=256, BK=256B. Grid 256 (1/CU), 512 thr = 8 waves (2m x 4n),
//   wave tile 64x64 -> acc[4][4]. 8 K-iterations, 2 barriers each.
//   Per-CU per-128B-K-step: MFMA 1305 cyc/SIMD vs LDS ~800 cyc -> MFMA-bound
//   (R8 was 2300-cyc LDS-bound; that's the 2x this attacks).
// Pipeline (counted vmcnt, never 0 mid-loop):
//   iter kt: STAGE_A(kt+1)[4 gll] | vmcnt(12) barrier | ds_read a-h0, MFMA h0 (b0)
//            loadB(2kt+2)->b0[8] | ds_read a-h1, vmcnt(8), MFMA h1 (b1)
//            loadB(2kt+3)->b1[8] | lgkmcnt(0) barrier
//   vmcnt(12) = newer-than-B(2kt) in flight (B(2kt+1) 8 + A(kt+1) 4); covers A(kt) too.
// XCD swizzle: xcd=b&7 owns 8mt x 4nt -> 2MB A + 2MB B panels = one XCD L2.
// A LDS chunk swizzle (proven 0-conflict): LDS[r][s] holds 16B-chunk s ^ (r&7),
//   via pre-swizzled global source (linear gll dest).
__global__ __launch_bounds__(512) void lstm_gemm(
    const int8_t* __restrict__ Xhq, const int8_t* __restrict__ Wq2,
    const float* __restrict__ bqp, const float* __restrict__ cin,
    float* __restrict__ hout, float* __restrict__ cout_)
{
    __shared__ __align__(16) char raw[65536];   // A dbuf 2 x 32KB; epilogue aliases
    const int t = threadIdx.x;          // 0..511
    const int l = t & 63;
    const int wave = t >> 6;            // 0..7
    const int wm = wave >> 2;           // 0..1  (64 m-rows each)
    const int wn = wave & 3;            // 0..3  (64 n-cols each)

    // XCD-aware remap: 256 blocks = 8 xcd x 32 slot (bijective)
    const int b = blockIdx.x;
    const int xcd = b & 7;
    const int slot = b >> 3;            // 0..31
    const int mt = ((xcd & 1) << 3) + (slot & 7);    // 0..15
    const int nt = ((xcd >> 1) << 2) + (slot >> 3);  // 0..15
    const int m0 = mt * 128;
    const int n0 = nt * 256;

    v4i acc[4][4];
    #pragma unroll
    for (int i = 0; i < 4; ++i)
        #pragma unroll
        for (int j = 0; j < 4; ++j)
            acc[i][j] = (v4i)0;

    // A staging: thread t covers rows {32*i + (t>>4)}, chunk-slot t&15 (of 16 per 256B row).
    // LDS slot (r, s) holds global chunk s ^ (r&7); (32*i + r)&7 == r&7.
    const int srow = t >> 4;                      // 0..31
    const int schunk = (t & 15) ^ (srow & 7);
    const int8_t* gA = Xhq + (size_t)(m0 + srow) * K_DIM + schunk * 16;

#define STAGE_A(kt) do { \
    char* Ad_ = raw + (((kt) & 1) ? 32768 : 0); \
    _Pragma("unroll") \
    for (int i_ = 0; i_ < 4; ++i_) { \
        __builtin_amdgcn_global_load_lds( \
            (const __attribute__((address_space(1))) uint32_t*)(gA + (size_t)(i_) * 65536 + (size_t)(kt) * 256), \
            (__attribute__((address_space(3))) uint32_t*)(Ad_ + i_ * 8192 + t * 16), 16, 0, 0); \
    } \
} while (0)

    // B fragment loads: per half h (128B of K), 8 frags (kk x nf), each coalesced.
    const int8_t* gBw = Wq2 + (((size_t)(n0 >> 4) + wn * 4) << 15) + (size_t)l * 16;
#define LOADB(dst, h) do { \
    _Pragma("unroll") \
    for (int nf_ = 0; nf_ < 4; ++nf_) \
        _Pragma("unroll") \
        for (int kk_ = 0; kk_ < 2; ++kk_) \
            dst[kk_][nf_] = *(const v4i*)(gBw + ((size_t)nf_ << 15) + (size_t)((h) * 2 + kk_) * 1024); \
} while (0)

    v4i b0[2][4], b1[2][4];
    // Prologue: A(0) staged; B halves 0,1 in flight.
    STAGE_A(0);
    LOADB(b0, 0);
    LOADB(b1, 1);

    const int rrow = l & 15;
    const int lx = l & 7;
    const int g4 = l >> 4;              // 0..3

    for (int kt = 0; kt < 8; ++kt) {
        const char* As = raw + ((kt & 1) ? 32768 : 0);
        if (kt < 7) STAGE_A(kt + 1);
        // Need A(kt) and b0 = B(2kt) landed. Newer in flight: B(2kt+1)=8 + A(kt+1)=4.
        if (kt < 7) asm volatile("s_waitcnt vmcnt(12)" ::: "memory");
        else        asm volatile("s_waitcnt vmcnt(8)" ::: "memory");
        asm volatile("s_barrier" ::: "memory");

        // ---- half 0: k-steps s=0,1 ----
        {
            v4i a[2][4];
            #pragma unroll
            for (int kk = 0; kk < 2; ++kk) {
                const int sl = ((kk * 4 + g4) ^ lx) * 16;
                #pragma unroll
                for (int mf = 0; mf < 4; ++mf)
                    a[kk][mf] = *(const v4i*)(As + (size_t)(wm * 64 + mf * 16 + rrow) * 256 + sl);
            }
            #pragma unroll
            for (int kk = 0; kk < 2; ++kk)
                #pragma unroll
                for (int mf = 0; mf < 4; ++mf)
                    #pragma unroll
                    for (int nf = 0; nf < 4; ++nf)
                        acc[mf][nf] = __builtin_amdgcn_mfma_i32_16x16x64_i8(
                            a[kk][mf], b0[kk][nf], acc[mf][nf], 0, 0, 0);
        }
        if (kt < 7) LOADB(b0, 2 * kt + 2);
        // ---- half 1: k-steps s=2,3 ----
        {
            v4i a[2][4];
            #pragma unroll
            for (int kk = 0; kk < 2; ++kk) {
                const int sl = (((2 + kk) * 4 + g4) ^ lx) * 16;
                #pragma unroll
                for (int mf = 0; mf < 4; ++mf)
                    a[kk][mf] = *(const v4i*)(As + (size_t)(wm * 64 + mf * 16 + rrow) * 256 + sl);
            }
            // Need b1 = B(2kt+1): newer in flight = B(2kt+2) (8) if staged.
            if (kt < 7) asm volatile("s_waitcnt vmcnt(8)" ::: "memory");
            else        asm volatile("s_waitcnt vmcnt(0)" ::: "memory");
            #pragma unroll
            for (int kk = 0; kk < 2; ++kk)
                #pragma unroll
                for (int mf = 0; mf < 4; ++mf)
                    #pragma unroll
                    for (int nf = 0; nf < 4; ++nf)
                        acc[mf][nf] = __builtin_amdgcn_mfma_i32_16x16x64_i8(
                            a[kk][mf], b1[kk][nf], acc[mf][nf], 0, 0, 0);
        }
        if (kt < 7) LOADB(b1, 2 * kt + 3);
        asm volatile("s_waitcnt lgkmcnt(0)" ::: "memory");   // LDS reads done before overwrite
        asm volatile("s_barrier" ::: "memory");
    }

#undef STAGE_A
#undef LOADB

    // Epilogue: four 32-row quarters through an LDS C-tile (aliases A dbuf).
    // Quarter q rows [q*32, +32): wm = q>>1, mf = (q&1)*2 + {0,1}.
    float (*Cs)[264] = (float(*)[264])raw;   // [32][264] f32 = 33792 B
    const float sc = 0.0009765625f;          // 2^-10
    for (int q = 0; q < 4; ++q) {
        __syncthreads();
        if (wm == (q >> 1)) {
            #pragma unroll
            for (int mf2 = 0; mf2 < 2; ++mf2) {
                const int mf = (q & 1) * 2 + mf2;
                const int rb = mf2 * 16 + ((l >> 4) << 2);
                #pragma unroll
                for (int nf = 0; nf < 4; ++nf) {
                    const int col = wn * 64 + nf * 16 + (l & 15);
                    #pragma unroll
                    for (int rr = 0; rr < 4; ++rr)
                        Cs[rb + rr][col] = (float)acc[mf][nf][rr] * sc;
                }
            }
        }
        __syncthreads();
        #pragma unroll
        for (int it = 0; it < 4; ++it) {
            const int idx = it * 512 + t;        // 0..2047 = 32 rows x 64 j
            const int row = idx >> 6;
            const int jl = idx & 63;
            float4 y = *(const float4*)&Cs[row][jl << 2];
            float4 bv = *(const float4*)&bqp[n0 + (jl << 2)];
            const int m = m0 + q * 32 + row;
            const int j = (n0 >> 2) + jl;
            const float ig = fqf(fsigm(y.x + bv.x));
            const float fg = fqf(fsigm(y.y + bv.y));
            const float gg = fqf(ftanh(y.z + bv.z));
            const float og = fqf(fsigm(y.w + bv.w));
            const float cq = fqf(cin[(size_t)m * 1024 + j]);
            const float cn = cq * fg + ig * gg;
            const float hn = fqf(ftanh(cn)) * og;
            hout[(size_t)m * 1024 + j] = hn;
            cout_[(size_t)m * 1024 + j] = cn;
        }
    }
}

extern "C" void kernel_launch(void* const* d_in, const int* in_sizes, int n_in,
                              void* d_out, int out_size, void* d_ws, size_t ws_size,
                              hipStream_t stream) {
    const float* X    = (const float*)d_in[0];   // [2048,1024]
    const float* h    = (const float*)d_in[1];   // [2048,1024]
    const float* c    = (const float*)d_in[2];   // [2048,1024]
    const float* W    = (const float*)d_in[3];   // [4096,2048]
    const float* bias = (const float*)d_in[4];   // [4096]

    float* out   = (float*)d_out;
    float* h_out = out;                          // [2048,1024]
    float* c_out = out + (size_t)B_DIM * 1024;   // [2048,1024]

    char* ws = (char*)d_ws;
    int8_t* Xhq = (int8_t*)ws;                              // 4 MB
    int8_t* Wq2 = (int8_t*)(ws + (size_t)4 * 1024 * 1024);  // 8 MB (fragment-packed)
    float*  bqp = (float*)(ws + (size_t)12 * 1024 * 1024);  // 16 KB

    quant_pack<<<B_DIM + 256 + 1, 256, 0, stream>>>(X, h, W, bias, Xhq, Wq2, bqp);

    lstm_gemm<<<256, 512, 0, stream>>>(Xhq, Wq2, bqp, c, h_out, c_out);
}

// Round 3
// 42.397 us; speedup vs baseline: 1.4979x; 1.4979x over previous
//
#include <hip/hip_runtime.h>
#include <stdint.h>

#define B_DIM 2048
#define K_DIM 2048
#define N_PACK 4096

typedef int v4i __attribute__((ext_vector_type(4)));

__device__ __forceinline__ float fqf(float x) {
    float q = rintf(x * 32.0f);
    q = fminf(fmaxf(q, -128.0f), 127.0f);
    return q * 0.03125f;
}
__device__ __forceinline__ int q8i(float x) {
    float q = rintf(x * 32.0f);
    q = fminf(fmaxf(q, -128.0f), 127.0f);
    return (int)q;
}
__device__ __forceinline__ float fsigm(float x) {
    return __fdividef(1.0f, 1.0f + __expf(-x));
}
__device__ __forceinline__ float ftanh(float x) {
    return __fdividef(2.0f, 1.0f + __expf(-2.0f * x)) - 1.0f;
}

// One kernel quantizes everything (R8-proven version, at HBM roofline):
//  blocks [0, 2048)        : Xh rows  -> Xhq[m][k] int8, k<1024 from X, else h
//  blocks [2048, 6144)     : W rows   -> Wq[p][k] int8, packed p = j*4 + gate
//  block  6144             : bias     -> bqp[j*4 + gate] (fake-quantized f32)
__global__ __launch_bounds__(256) void quant_pack(
    const float* __restrict__ X, const float* __restrict__ hI,
    const float* __restrict__ W, const float* __restrict__ bias,
    int8_t* __restrict__ Xhq, int8_t* __restrict__ Wq, float* __restrict__ bqp)
{
    const int bid = blockIdx.x;
    const int t = threadIdx.x;
    if (bid < B_DIM) {
        const int m = bid;
        const int k0 = t * 8;
        const float* src = (k0 < 1024) ? (X + (size_t)m * 1024 + k0)
                                       : (hI + (size_t)m * 1024 + (k0 - 1024));
        float4 v0 = *(const float4*)src;
        float4 v1 = *(const float4*)(src + 4);
        union { int8_t c[8]; int64_t ll; } u;
        u.c[0] = (int8_t)q8i(v0.x); u.c[1] = (int8_t)q8i(v0.y);
        u.c[2] = (int8_t)q8i(v0.z); u.c[3] = (int8_t)q8i(v0.w);
        u.c[4] = (int8_t)q8i(v1.x); u.c[5] = (int8_t)q8i(v1.y);
        u.c[6] = (int8_t)q8i(v1.z); u.c[7] = (int8_t)q8i(v1.w);
        *(int64_t*)(Xhq + (size_t)m * K_DIM + k0) = u.ll;
    } else if (bid < B_DIM + N_PACK) {
        const int r = bid - B_DIM;          // original weight row (gate*1024 + j)
        const int gate = r >> 10, j = r & 1023;
        const int p = (j << 2) | gate;      // packed row
        const int k0 = t * 8;
        const float* src = W + (size_t)r * K_DIM + k0;
        float4 v0 = *(const float4*)src;
        float4 v1 = *(const float4*)(src + 4);
        union { int8_t c[8]; int64_t ll; } u;
        u.c[0] = (int8_t)q8i(v0.x); u.c[1] = (int8_t)q8i(v0.y);
        u.c[2] = (int8_t)q8i(v0.z); u.c[3] = (int8_t)q8i(v0.w);
        u.c[4] = (int8_t)q8i(v1.x); u.c[5] = (int8_t)q8i(v1.y);
        u.c[6] = (int8_t)q8i(v1.z); u.c[7] = (int8_t)q8i(v1.w);
        *(int64_t*)(Wq + (size_t)p * K_DIM + k0) = u.ll;
    } else {
        for (int idx = t; idx < N_PACK; idx += 256) {
            const int gate = idx >> 10, j = idx & 1023;
            bqp[(j << 2) | gate] = fqf(bias[idx]);
        }
    }
}

// GEMM C[2048][4096p] = Xhq @ Wq^T (int8 -> i32, exact), fused LSTM epilogue.
// R11 = R8 skeleton (proven 41 us: grid 512, BM=BN=128, BK=128B, 2-barrier
// counted-vmcnt loop, 0-conflict chunk-XOR LDS swizzle, XCD swizzle, LDS-C
// epilogue, 64KB LDS -> 2 blocks/CU) with ONE change: 4 waves (256 thr) in a
// 2x2 grid of 64x64 wave tiles instead of 8 waves of 64x32.
//   Why: R8 is LDS-read-bound (3 MB frag-reads/CU = 15.4 us floor vs 8.7 us
//   MFMA floor). Square tiles cut LDS bytes/MFMA 0.75 -> 0.5 KB: 2 MB/CU
//   (10.3 us floor). R10 proved B must stay in LDS (global-B = L2 meltdown)
//   and that losing the 2nd co-resident block is fatal -> keep both.
__global__ __launch_bounds__(256, 2) void lstm_gemm(
    const int8_t* __restrict__ Xhq, const int8_t* __restrict__ Wq,
    const float* __restrict__ bqp, const float* __restrict__ cin,
    float* __restrict__ hout, float* __restrict__ cout_)
{
    __shared__ __align__(16) char raw[65536];   // 2 x (A 16K + B 16K); epilogue aliases
    const int t = threadIdx.x;          // 0..255
    const int l = t & 63;
    const int wave = t >> 6;            // 0..3
    const int wm = wave >> 1;           // 0..1  (64 m-rows each)
    const int wn = wave & 1;            // 0..1  (64 packed cols each)

    // XCD-aware remap (1-D grid, 512 blocks, bijective; R8-proven)
    const int b = blockIdx.x;
    const int xcd = b & 7;
    const int slot = b >> 3;            // 0..63
    const int mt = ((xcd & 1) << 3) + (slot & 7);    // 0..15
    const int nt = ((xcd >> 1) << 3) + (slot >> 3);  // 0..31
    const int m0 = mt * 128;
    const int n0 = nt * 128;

    v4i acc[4][4];
    #pragma unroll
    for (int i = 0; i < 4; ++i)
        #pragma unroll
        for (int j = 0; j < 4; ++j)
            acc[i][j] = (v4i)0;

    // staging: thread t covers rows {srow + 32*i}, chunk-slot t&7.
    // LDS slot (r, s) holds global chunk s ^ (r&7); (srow+32i)&7 == srow&7.
    const int srow = t >> 3;                      // 0..31
    const int schunk = (t & 7) ^ (srow & 7);
    const int8_t* gA = Xhq + (size_t)(m0 + srow) * K_DIM + schunk * 16;
    const int8_t* gB = Wq  + (size_t)(n0 + srow) * K_DIM + schunk * 16;

#define STAGE(p, kt) do { \
    char* Ad_ = raw + (p) * 32768; \
    char* Bd_ = raw + (p) * 32768 + 16384; \
    _Pragma("unroll") \
    for (int i_ = 0; i_ < 4; ++i_) { \
        __builtin_amdgcn_global_load_lds( \
            (const __attribute__((address_space(1))) uint32_t*)(gA + (size_t)(i_ * 32) * K_DIM + (kt) * 128), \
            (__attribute__((address_space(3))) uint32_t*)(Ad_ + i_ * 4096 + t * 16), 16, 0, 0); \
        __builtin_amdgcn_global_load_lds( \
            (const __attribute__((address_space(1))) uint32_t*)(gB + (size_t)(i_ * 32) * K_DIM + (kt) * 128), \
            (__attribute__((address_space(3))) uint32_t*)(Bd_ + i_ * 4096 + t * 16), 16, 0, 0); \
    } \
} while (0)

    STAGE(0, 0);

    const int rrow = l & 15;
    const int lx = l & 7;   // == r&7 for all fragment rows (rows are 16-multiples + rrow)
    const int g4 = l >> 4;  // 0..3

    for (int kt = 0; kt < 16; ++kt) {
        const int p = kt & 1;
        if (kt < 15) {
            STAGE(p ^ 1, kt + 1);
            asm volatile("s_waitcnt vmcnt(8)" ::: "memory");  // tile kt landed; kt+1 in flight
        } else {
            asm volatile("s_waitcnt vmcnt(0)" ::: "memory");
        }
        asm volatile("s_barrier" ::: "memory");

        const char* As = raw + p * 32768;
        const char* Bs = raw + p * 32768 + 16384;
        v4i a[2][4], b2[2][4];
        #pragma unroll
        for (int kk = 0; kk < 2; ++kk) {
            const int c = kk * 4 + g4;
            const int sl = (c ^ lx) * 16;
            #pragma unroll
            for (int mf = 0; mf < 4; ++mf) {
                const int r = wm * 64 + mf * 16 + rrow;
                a[kk][mf] = *(const v4i*)(As + r * 128 + sl);
            }
            #pragma unroll
            for (int nf = 0; nf < 4; ++nf) {
                const int r = wn * 64 + nf * 16 + rrow;
                b2[kk][nf] = *(const v4i*)(Bs + r * 128 + sl);
            }
        }
        #pragma unroll
        for (int kk = 0; kk < 2; ++kk)
            #pragma unroll
            for (int mf = 0; mf < 4; ++mf)
                #pragma unroll
                for (int nf = 0; nf < 4; ++nf)
                    acc[mf][nf] = __builtin_amdgcn_mfma_i32_16x16x64_i8(
                        a[kk][mf], b2[kk][nf], acc[mf][nf], 0, 0, 0);
        asm volatile("s_waitcnt lgkmcnt(0)" ::: "memory");   // LDS reads done before overwrite
        asm volatile("s_barrier" ::: "memory");
    }

#undef STAGE

    // Epilogue: two 64-row halves through an LDS C-tile (aliases staging bufs).
    // Half h rows [h*64, +64): owned by the 2 waves with wm == h (wn = 0,1).
    float (*Cs)[132] = (float(*)[132])raw;   // [64][132] f32 = 33792 B
    const float sc = 0.0009765625f;          // 2^-10
    for (int half = 0; half < 2; ++half) {
        __syncthreads();
        if (wm == half) {
            #pragma unroll
            for (int mf = 0; mf < 4; ++mf) {
                const int rb = mf * 16 + ((l >> 4) << 2);
                #pragma unroll
                for (int nf = 0; nf < 4; ++nf) {
                    const int col = wn * 64 + nf * 16 + (l & 15);
                    #pragma unroll
                    for (int rr = 0; rr < 4; ++rr)
                        Cs[rb + rr][col] = (float)acc[mf][nf][rr] * sc;
                }
            }
        }
        __syncthreads();
        #pragma unroll
        for (int it = 0; it < 8; ++it) {
            const int idx = it * 256 + t;        // 0..2047 = 64 rows x 32 j
            const int row = idx >> 5;
            const int jl = idx & 31;
            float4 y = *(const float4*)&Cs[row][jl << 2];
            float4 bb = *(const float4*)&bqp[n0 + (jl << 2)];
            const int m = m0 + half * 64 + row;
            const int j = (n0 >> 2) + jl;
            const float ig = fqf(fsigm(y.x + bb.x));
            const float fg = fqf(fsigm(y.y + bb.y));
            const float gg = fqf(ftanh(y.z + bb.z));
            const float og = fqf(fsigm(y.w + bb.w));
            const float cq = fqf(cin[(size_t)m * 1024 + j]);
            const float cn = cq * fg + ig * gg;
            const float hn = fqf(ftanh(cn)) * og;
            hout[(size_t)m * 1024 + j] = hn;
            cout_[(size_t)m * 1024 + j] = cn;
        }
    }
}

extern "C" void kernel_launch(void* const* d_in, const int* in_sizes, int n_in,
                              void* d_out, int out_size, void* d_ws, size_t ws_size,
                              hipStream_t stream) {
    const float* X    = (const float*)d_in[0];   // [2048,1024]
    const float* h    = (const float*)d_in[1];   // [2048,1024]
    const float* c    = (const float*)d_in[2];   // [2048,1024]
    const float* W    = (const float*)d_in[3];   // [4096,2048]
    const float* bias = (const float*)d_in[4];   // [4096]

    float* out   = (float*)d_out;
    float* h_out = out;                          // [2048,1024]
    float* c_out = out + (size_t)B_DIM * 1024;   // [2048,1024]

    char* ws = (char*)d_ws;
    int8_t* Xhq = (int8_t*)ws;                              // 4 MB
    int8_t* Wq  = (int8_t*)(ws + (size_t)4 * 1024 * 1024);  // 8 MB
    float*  bqp = (float*)(ws + (size_t)12 * 1024 * 1024);  // 16 KB

    quant_pack<<<B_DIM + N_PACK + 1, 256, 0, stream>>>(X, h, W, bias, Xhq, Wq, bqp);

    lstm_gemm<<<512, 256, 0, stream>>>(Xhq, Wq, bqp, c, h_out, c_out);
}